// Round 9
// baseline (1950.541 us; speedup 1.0000x reference)
//
#include <hip/hip_runtime.h>
#include <hip/hip_bf16.h>
#include <cstdint>
#include <cstddef>

#define B_ 128
#define T_ 1024
#define D_ 256
#define U_ 256

typedef __bf16 bfrag __attribute__((ext_vector_type(8)));
typedef unsigned short us8 __attribute__((ext_vector_type(8)));
typedef float f32x4 __attribute__((ext_vector_type(4)));

// Gate input pre-scales folded into weights/bias so the hot loop's sigmoid
// and tanh need no multiply:  sigm(x)=rcp(1+exp2(-1.4427x)),
// tanh(x)=1-2*rcp(1+exp2(2.8854x)).
#define SC_ZR (-1.4426950408889634f)
#define SC_H  (2.8853900817779268f)

__device__ __forceinline__ unsigned short f2bf(float f) {
    unsigned int u = __builtin_bit_cast(unsigned int, f);
    unsigned int r = (u + 0x7fffu + ((u >> 16) & 1u)) >> 16;
    return (unsigned short)r;
}
__device__ __forceinline__ float bf2f(unsigned short h) {
    unsigned int u = ((unsigned int)h) << 16;
    return __builtin_bit_cast(float, u);
}
// HW packed f32->2xbf16 (RNE). ONLY in one-shot paths (wt/proj);
// inline asm in gru's hot loop perturbed scheduling (R3 lesson).
__device__ __forceinline__ unsigned int pk_bf16(float lo, float hi) {
    unsigned int d;
    asm("v_cvt_pk_bf16_f32 %0, %1, %2" : "=v"(d) : "v"(lo), "v"(hi));
    return d;
}
// Cheap 3-op pack for the hot loop: round-half-up + v_perm_b32 byte gather.
__device__ __forceinline__ unsigned int pk_hu(float lo, float hi) {
    unsigned int a = __builtin_bit_cast(unsigned int, lo) + 0x8000u;
    unsigned int b = __builtin_bit_cast(unsigned int, hi) + 0x8000u;
#if __has_builtin(__builtin_amdgcn_perm)
    return __builtin_amdgcn_perm(b, a, 0x07060302u);  // [b.hi16 : a.hi16]
#else
    return (b & 0xffff0000u) | (a >> 16);
#endif
}

#if __has_builtin(__builtin_amdgcn_exp2f)
__device__ __forceinline__ float fexp2(float x) { return __builtin_amdgcn_exp2f(x); }
#else
__device__ __forceinline__ float fexp2(float x) { return exp2f(x); }
#endif
#if __has_builtin(__builtin_amdgcn_rcpf)
__device__ __forceinline__ float frcp(float x) { return __builtin_amdgcn_rcpf(x); }
#else
__device__ __forceinline__ float frcp(float x) { return 1.0f / x; }
#endif

__device__ __forceinline__ float sigm_pre(float zp) {
    return frcp(1.0f + fexp2(zp));
}
__device__ __forceinline__ float tanh_pre(float sp) {
    return 1.0f - 2.0f * frcp(1.0f + fexp2(sp));
}

// lgkm-only barrier: LDS writes visible, in-flight global loads NOT drained
#define BARRIER_LGKM() asm volatile("s_waitcnt lgkmcnt(0)\n\ts_barrier" ::: "memory")

// xzh layout: [gb(32)][t(1024)][col(768)][b4(4)] bf16 (proven R4: sequential
// per-block streams). col<512: xz+b_zr; col>=512: xh+b_h.
#define TSTR2 3072                       // shorts per t within a gb stream
#define GSTR  ((size_t)T_ * TSTR2)       // shorts per gb group
#define WTSZ  (768 * 256)                // shorts per Wt copy

// ---------------------------------------------------------------------------
// wt_kernel: Wt[col(768)][k(256)] bf16 = transpose of [W_zr | W_h] with the
// gate pre-scale folded in, replicated `ncopies` times for L2 locality.
// ---------------------------------------------------------------------------
__global__ __launch_bounds__(64) void wt_kernel(
    const float* __restrict__ Wzr, const float* __restrict__ Wh,
    unsigned short* __restrict__ Wt, int ncopies)
{
    const int c = blockIdx.x;      // 0..767
    const int lane = threadIdx.x;  // 0..63
    const float* Wp; int ldw, cc;
    if (c < 512) { Wp = Wzr; ldw = 512; cc = c; }
    else         { Wp = Wh;  ldw = 256; cc = c - 512; }
    const float sc = (c < 512) ? SC_ZR : SC_H;
    const int k0 = lane * 4;
    const float a = sc * Wp[(size_t)(k0 + 0) * ldw + cc];
    const float b = sc * Wp[(size_t)(k0 + 1) * ldw + cc];
    const float d = sc * Wp[(size_t)(k0 + 2) * ldw + cc];
    const float e = sc * Wp[(size_t)(k0 + 3) * ldw + cc];
    uint2 u; u.x = pk_bf16(a, b); u.y = pk_bf16(d, e);
    for (int r = 0; r < ncopies; ++r)
        *reinterpret_cast<uint2*>(&Wt[(size_t)r * WTSZ + (size_t)c * 256 + k0]) = u;
}

// ---------------------------------------------------------------------------
// fused_kernel: blocks 0..31 = gru (R5 body + slab gating + prio), blocks
// 32..1055 = proj. R9 change vs R8 (one variable, proj path only): the Wt
// chunk loads are software-pipelined with an explicit register double-buffer
// (ping-pong by name, 2-phase unrolled loop). The old `#pragma unroll 1`
// chunk loop serialized {16 L2 loads -> wait -> 32 MFMA} x12, making proj
// latency-bound (~150 TF, ~300us standalone; first slab late by a full block
// latency). Now chunk n+1's loads fly under chunk n's MFMA+epilogue.
// gru path byte-identical to R8 (proven). LDS 82432 keeps 1 block/CU.
// ---------------------------------------------------------------------------
#define LPA 296           // proj ldsA row pad (shorts); 592 B rows, 16-B aligned
#define HBP 272           // gru shorts per row (544 B)
#define HB4 (4 * HBP)     // gru shorts per hb buffer

__global__ __launch_bounds__(512, 1) void fused_kernel(
    const float* __restrict__ x, const unsigned short* __restrict__ Wt,
    const float* __restrict__ bzr, const float* __restrict__ bh,
    unsigned short* __restrict__ xzh, size_t wtstride,
    const float* __restrict__ Uzr, const float* __restrict__ Uh,
    float* __restrict__ out, unsigned int* __restrict__ flags)
{
    const int bid = blockIdx.x;
    const int tid = threadIdx.x;

    if (bid >= 32) {
        // =================== proj path (prio 0) ===================
        const int p    = bid - 32;
        const int tb8  = p >> 3;        // 0..127  (t-major: early t first)
        const int bb   = p & 7;         // 0..7
        const int lane = tid & 63;
        const int wv8  = tid >> 6;      // 0..7
        const int gidx = wv8 >> 2;      // tile group 0/1 (t-window)
        const int wl   = wv8 & 3;       // wave-local 0..3 (old wv)
        const int q    = lane >> 4;
        const int c16  = lane & 15;
        const int tbe  = tb8 * 2 + gidx;  // effective old tb 0..255

        __shared__ __align__(16) unsigned short ldsA[2][64 * LPA];

        // ---- stage A (64 rows x 256 k) per group, coalesced ----
        {
            const int r0 = wl * 16;
#pragma unroll
            for (int r = 0; r < 16; ++r) {
                const int row = r0 + r;
                const float* xr = x + (((size_t)(bb * 16 + (row & 15))) * T_
                                       + tbe * 4 + (row >> 4)) * D_;
                f32x4 v = *reinterpret_cast<const f32x4*>(xr + lane * 4);
                uint2 u; u.x = pk_bf16(v[0], v[1]); u.y = pk_bf16(v[2], v[3]);
                *reinterpret_cast<uint2*>(&ldsA[gidx][row * LPA + lane * 4]) = u;
            }
        }
        __syncthreads();

        const int R0 = (wl >> 1) * 32;
        us8 af[2][8];
#pragma unroll
        for (int m2 = 0; m2 < 2; ++m2)
#pragma unroll
            for (int kk = 0; kk < 8; ++kk)
                af[m2][kk] = *reinterpret_cast<const us8*>(
                    &ldsA[gidx][(R0 + m2 * 16 + c16) * LPA + kk * 32 + q * 8]);

        const int wn = wl & 1;
        const unsigned short* p0 = Wt + (size_t)bb * wtstride
                                   + ((size_t)(wn * 32 + c16) * 256 + q * 8);
        const unsigned short* p1 = p0 + 16 * 256;

        // compute+store for one 64-col chunk from a register weight buffer
        auto compute_store = [&](const us8 (&w0)[8], const us8 (&w1)[8],
                                 const int ch) {
            f32x4 acc[2][2] = {};
#pragma unroll
            for (int kk = 0; kk < 8; ++kk) {
#pragma unroll
                for (int m2 = 0; m2 < 2; ++m2) {
                    acc[m2][0] = __builtin_amdgcn_mfma_f32_16x16x32_bf16(
                        __builtin_bit_cast(bfrag, af[m2][kk]),
                        __builtin_bit_cast(bfrag, w0[kk]), acc[m2][0], 0, 0, 0);
                    acc[m2][1] = __builtin_amdgcn_mfma_f32_16x16x32_bf16(
                        __builtin_bit_cast(bfrag, af[m2][kk]),
                        __builtin_bit_cast(bfrag, w1[kk]), acc[m2][1], 0, 0, 0);
                }
            }
#pragma unroll
            for (int n2 = 0; n2 < 2; ++n2) {
                const int gcn = ch * 64 + wn * 32 + n2 * 16 + c16;
                const float bias = (gcn < 512) ? (SC_ZR * bzr[gcn])
                                               : (SC_H * bh[gcn - 512]);
#pragma unroll
                for (int m2 = 0; m2 < 2; ++m2) {
                    const int t = tbe * 4 + (wl >> 1) * 2 + m2;
                    uint2 uu;
                    uu.x = pk_bf16(acc[m2][n2][0] + bias, acc[m2][n2][1] + bias);
                    uu.y = pk_bf16(acc[m2][n2][2] + bias, acc[m2][n2][3] + bias);
                    *reinterpret_cast<uint2*>(
                        &xzh[((((size_t)(bb * 4 + q)) * T_ + t) * 768 + gcn) * 4]) = uu;
                }
            }
        };

        // software pipeline: double-buffered Wt chunks, ping-pong by name
        us8 cw0[8], cw1[8];
#pragma unroll
        for (int kk = 0; kk < 8; ++kk) {
            cw0[kk] = *reinterpret_cast<const us8*>(p0 + kk * 32);
            cw1[kk] = *reinterpret_cast<const us8*>(p1 + kk * 32);
        }
#pragma unroll 1
        for (int ch2 = 0; ch2 < 6; ++ch2) {
            us8 nw0[8], nw1[8];
            p0 += 64 * 256; p1 += 64 * 256;
#pragma unroll
            for (int kk = 0; kk < 8; ++kk) {
                nw0[kk] = *reinterpret_cast<const us8*>(p0 + kk * 32);
                nw1[kk] = *reinterpret_cast<const us8*>(p1 + kk * 32);
            }
            compute_store(cw0, cw1, ch2 * 2);
            p0 += 64 * 256; p1 += 64 * 256;
            if (ch2 < 5) {
#pragma unroll
                for (int kk = 0; kk < 8; ++kk) {
                    cw0[kk] = *reinterpret_cast<const us8*>(p0 + kk * 32);
                    cw1[kk] = *reinterpret_cast<const us8*>(p1 + kk * 32);
                }
            }
            compute_store(nw0, nw1, ch2 * 2 + 1);
        }

        // publish: all waves' stores visible, then release the slab flag
        __threadfence();
        __syncthreads();
        if (tid == 0)
            __hip_atomic_store(&flags[bb * 128 + tb8], 1u,
                               __ATOMIC_RELEASE, __HIP_MEMORY_SCOPE_AGENT);
        return;
    }

    // =================== gru path (R5 body + slab gating, prio 1) ==========
    const int lane = tid & 63;
    const int w    = tid >> 6;
    const int q    = lane >> 4;
    const int c16  = lane & 15;
    const int g    = bid;               // 0..31, batch rows g*4 .. g*4+3
    const unsigned int* fl = flags + (g >> 2) * 128;

    __shared__ __align__(16) unsigned short hb[2 * HB4];   // ping-pong h
    __shared__ __align__(16) unsigned short rhb[HB4];

    // weight preload, k-perm: position p=kk*32+q*8+j holds h-row
    // kr = kk*32 + q*4 + (j>>1) + 16*(j&1); gate scale folded in.
    us8 wA[4][8];
#pragma unroll
    for (int nt = 0; nt < 4; ++nt) {
        const int col = (nt < 2) ? (w * 32 + nt * 16 + c16)
                                 : (256 + w * 32 + (nt - 2) * 16 + c16);
#pragma unroll
        for (int kk = 0; kk < 8; ++kk) {
            us8 v;
#pragma unroll
            for (int j = 0; j < 8; ++j) {
                const int kr = kk * 32 + q * 4 + (j >> 1) + 16 * (j & 1);
                v[j] = f2bf(SC_ZR * Uzr[(size_t)kr * 512 + col]);
            }
            wA[nt][kk] = v;
        }
    }
    us8 wB[2][8];
#pragma unroll
    for (int nt = 0; nt < 2; ++nt) {
        const int col = w * 32 + nt * 16 + c16;
#pragma unroll
        for (int kk = 0; kk < 8; ++kk) {
            us8 v;
#pragma unroll
            for (int j = 0; j < 8; ++j) {
                const int kr = kk * 32 + q * 4 + (j >> 1) + 16 * (j & 1);
                v[j] = f2bf(SC_H * Uh[(size_t)kr * 256 + col]);
            }
            wB[nt][kk] = v;
        }
    }

    for (int i = tid; i < 2 * HB4; i += 512) hb[i] = 0;
    for (int i = tid; i < HB4; i += 512) rhb[i] = 0;
    __syncthreads();

    float h0 = 0.0f, h1 = 0.0f;

    size_t laneA[4], laneB[2];
#pragma unroll
    for (int nt = 0; nt < 4; ++nt) {
        const int col = (nt < 2) ? (w * 32 + nt * 16 + c16)
                                 : (256 + w * 32 + (nt - 2) * 16 + c16);
        laneA[nt] = (size_t)g * GSTR + (size_t)col * 4 + q;
    }
#pragma unroll
    for (int nt = 0; nt < 2; ++nt)
        laneB[nt] = (size_t)g * GSTR
                    + (size_t)(512 + w * 32 + nt * 16 + c16) * 4 + q;

    // gate slab 0 at prio 0 (sleep so the producer isn't starved)
    unsigned int sl_ok = 0;
    while (__hip_atomic_load(&fl[0], __ATOMIC_ACQUIRE,
                             __HIP_MEMORY_SCOPE_AGENT) == 0)
        __builtin_amdgcn_s_sleep(2);
    sl_ok = 1;

    unsigned short ca[4], cxh[2];
#pragma unroll
    for (int nt = 0; nt < 4; ++nt) ca[nt] = xzh[laneA[nt]];
#pragma unroll
    for (int nt = 0; nt < 2; ++nt) cxh[nt] = xzh[laneB[nt]];

    size_t toff = TSTR2;  // points at t+1 data

    const int dwr = q * HBP + w * 32 + 2 * c16;        // row-q packed-dword write
    const int ard = (c16 >> 2) * HBP + q * 8;          // A-frag read base (row dup)

    int rb = 0;  // hb read-buffer base (shorts); write = rb ^ HB4

    // recurrence is the chip-wide critical path
    __builtin_amdgcn_s_setprio(1);

#pragma unroll 1
    for (int t = 0; t < T_; ++t) {
        const int wb = rb ^ HB4;
        // gate + issue next step's prefetch (reads t+1; clamped at the tail)
        if (t < 1023) {
            const unsigned int s1 = (unsigned int)(t + 1) >> 3;
            if (s1 >= sl_ok) {
                __builtin_amdgcn_s_setprio(0);
                while (__hip_atomic_load(&fl[s1], __ATOMIC_ACQUIRE,
                                         __HIP_MEMORY_SCOPE_AGENT) == 0)
                    __builtin_amdgcn_s_sleep(2);
                __builtin_amdgcn_s_setprio(1);
                sl_ok = s1 + 1;
            }
        }
        unsigned short na[4], nxh[2];
#pragma unroll
        for (int nt = 0; nt < 4; ++nt) na[nt] = xzh[laneA[nt] + toff];
#pragma unroll
        for (int nt = 0; nt < 2; ++nt) nxh[nt] = xzh[laneB[nt] + toff];
        if (t < 1022) toff += TSTR2;

        // ---- A-fragments (h(t-1)) to regs, shared by R and Z chunks ----
        us8 afr[8];
#pragma unroll
        for (int kk = 0; kk < 8; ++kk)
            afr[kk] = *reinterpret_cast<const us8*>(&hb[rb + ard + kk * 32]);

        // ---- R chunk: r' = xr' + h @ U_zr'[, 256..511] ----
        f32x4 accR[2];
#pragma unroll
        for (int nt = 0; nt < 2; ++nt) {
            const float v = bf2f(ca[2 + nt]);
            accR[nt][0] = v; accR[nt][1] = v; accR[nt][2] = v; accR[nt][3] = v;
        }
#pragma unroll
        for (int kk = 0; kk < 8; ++kk) {
            bfrag af2 = __builtin_bit_cast(bfrag, afr[kk]);
            accR[0] = __builtin_amdgcn_mfma_f32_16x16x32_bf16(
                af2, __builtin_bit_cast(bfrag, wA[2][kk]), accR[0], 0, 0, 0);
            accR[1] = __builtin_amdgcn_mfma_f32_16x16x32_bf16(
                af2, __builtin_bit_cast(bfrag, wA[3][kk]), accR[1], 0, 0, 0);
        }
        // R-path: this lane owns batch q only (acc[..][0] == row q*4).
        {
            const float r0 = sigm_pre(accR[0][0]);
            const float r1 = sigm_pre(accR[1][0]);
            *reinterpret_cast<unsigned int*>(&rhb[dwr]) = pk_hu(r0 * h0, r1 * h1);
        }

        // ---- Z chunk (issue overlaps R's VALU chain) ----
        f32x4 accZ[2];
#pragma unroll
        for (int nt = 0; nt < 2; ++nt) {
            const float v = bf2f(ca[nt]);
            accZ[nt][0] = v; accZ[nt][1] = v; accZ[nt][2] = v; accZ[nt][3] = v;
        }
#pragma unroll
        for (int kk = 0; kk < 8; ++kk) {
            bfrag af2 = __builtin_bit_cast(bfrag, afr[kk]);
            accZ[0] = __builtin_amdgcn_mfma_f32_16x16x32_bf16(
                af2, __builtin_bit_cast(bfrag, wA[0][kk]), accZ[0], 0, 0, 0);
            accZ[1] = __builtin_amdgcn_mfma_f32_16x16x32_bf16(
                af2, __builtin_bit_cast(bfrag, wA[1][kk]), accZ[1], 0, 0, 0);
        }
        BARRIER_LGKM();   // rhb RAW (all waves' R-writes visible)

        // ---- S chunk: s' = xh' + (R*h) @ U_h' ----
        f32x4 acc2[2];
#pragma unroll
        for (int nt = 0; nt < 2; ++nt) {
            const float v = bf2f(cxh[nt]);
            acc2[nt][0] = v; acc2[nt][1] = v; acc2[nt][2] = v; acc2[nt][3] = v;
        }
#pragma unroll
        for (int kk = 0; kk < 8; ++kk) {
            bfrag rf = __builtin_bit_cast(bfrag,
                *reinterpret_cast<const us8*>(&rhb[ard + kk * 32]));
            acc2[0] = __builtin_amdgcn_mfma_f32_16x16x32_bf16(
                rf, __builtin_bit_cast(bfrag, wB[0][kk]), acc2[0], 0, 0, 0);
            acc2[1] = __builtin_amdgcn_mfma_f32_16x16x32_bf16(
                rf, __builtin_bit_cast(bfrag, wB[1][kk]), acc2[1], 0, 0, 0);
        }
        // gates + h update; write into the OTHER hb buffer (no WAR)
        {
            const float z0 = sigm_pre(accZ[0][0]);
            const float z1 = sigm_pre(accZ[1][0]);
            const float s0 = tanh_pre(acc2[0][0]);
            const float s1 = tanh_pre(acc2[1][0]);
            h0 = fmaf(z0, s0 - h0, h0);
            h1 = fmaf(z1, s1 - h1, h1);
            *reinterpret_cast<unsigned int*>(&hb[wb + dwr]) = pk_hu(h0, h1);
        }
        // rotate prefetch
#pragma unroll
        for (int nt = 0; nt < 4; ++nt) ca[nt] = na[nt];
#pragma unroll
        for (int nt = 0; nt < 2; ++nt) cxh[nt] = nxh[nt];
        BARRIER_LGKM();   // hb[wb] RAW for next step; rhb WAR for next R-path
        rb = wb;
    }

    __builtin_amdgcn_s_setprio(0);

    // ---- write h_last: batch g*4+q, cols w*32+c16 / +16 ----
    out[(size_t)(g * 4 + q) * 256 + w * 32 + c16] = h0;
    out[(size_t)(g * 4 + q) * 256 + w * 32 + 16 + c16] = h1;
}

extern "C" void kernel_launch(void* const* d_in, const int* in_sizes, int n_in,
                              void* d_out, int out_size, void* d_ws, size_t ws_size,
                              hipStream_t stream) {
    const float* x   = (const float*)d_in[0];
    const float* Wzr = (const float*)d_in[1];
    const float* Uzr = (const float*)d_in[2];
    const float* bzr = (const float*)d_in[3];
    const float* Wh  = (const float*)d_in[4];
    const float* Uh  = (const float*)d_in[5];
    const float* bh  = (const float*)d_in[6];
    float* out = (float*)d_out;

    // ws layout: [xzh 201326592 B][flags 4096 B][Wt replicas]
    const size_t xzhbytes = (size_t)32 * GSTR * 2;   // 201326592
    const size_t flagbytes = 4096;                    // 8*128 u32 + pad
    const size_t wtbytes  = (size_t)WTSZ * 2;        // 393216 per copy
    unsigned short* xzh = (unsigned short*)d_ws;
    unsigned int* flags = (unsigned int*)((char*)d_ws + xzhbytes);
    unsigned short* Wt  = (unsigned short*)((char*)d_ws + xzhbytes + flagbytes);
    int ncopies = (ws_size >= xzhbytes + flagbytes + 8 * wtbytes) ? 8 : 1;
    const size_t wtstride = (ncopies == 8) ? (size_t)WTSZ : 0;

    wt_kernel<<<dim3(768), dim3(64), 0, stream>>>(Wzr, Wh, Wt, ncopies);
    hipMemsetAsync(flags, 0, flagbytes, stream);
    fused_kernel<<<dim3(1056), dim3(512), 0, stream>>>(
        x, Wt, bzr, bh, xzh, wtstride, Uzr, Uh, out, flags);
}

// Round 10
// 1619.704 us; speedup vs baseline: 1.2043x; 1.2043x over previous
//
#include <hip/hip_runtime.h>
#include <hip/hip_bf16.h>
#include <cstdint>
#include <cstddef>

#define B_ 128
#define T_ 1024
#define D_ 256
#define U_ 256

typedef __bf16 bfrag __attribute__((ext_vector_type(8)));
typedef unsigned short us8 __attribute__((ext_vector_type(8)));
typedef float f32x4 __attribute__((ext_vector_type(4)));

// Gate input pre-scales folded into weights/bias so the hot loop's sigmoid
// and tanh need no multiply:  sigm(x)=rcp(1+exp2(-1.4427x)),
// tanh(x)=1-2*rcp(1+exp2(2.8854x)).
#define SC_ZR (-1.4426950408889634f)
#define SC_H  (2.8853900817779268f)

__device__ __forceinline__ unsigned short f2bf(float f) {
    unsigned int u = __builtin_bit_cast(unsigned int, f);
    unsigned int r = (u + 0x7fffu + ((u >> 16) & 1u)) >> 16;
    return (unsigned short)r;
}
__device__ __forceinline__ float bf2f(unsigned short h) {
    unsigned int u = ((unsigned int)h) << 16;
    return __builtin_bit_cast(float, u);
}
// HW packed f32->2xbf16 (RNE). ONLY in one-shot kernels (wt/proj);
// inline asm in gru_rec's hot loop perturbed scheduling (R3 lesson).
__device__ __forceinline__ unsigned int pk_bf16(float lo, float hi) {
    unsigned int d;
    asm("v_cvt_pk_bf16_f32 %0, %1, %2" : "=v"(d) : "v"(lo), "v"(hi));
    return d;
}
// Cheap 3-op pack for the hot loop: round-half-up + v_perm_b32 byte gather.
__device__ __forceinline__ unsigned int pk_hu(float lo, float hi) {
    unsigned int a = __builtin_bit_cast(unsigned int, lo) + 0x8000u;
    unsigned int b = __builtin_bit_cast(unsigned int, hi) + 0x8000u;
#if __has_builtin(__builtin_amdgcn_perm)
    return __builtin_amdgcn_perm(b, a, 0x07060302u);  // [b.hi16 : a.hi16]
#else
    return (b & 0xffff0000u) | (a >> 16);
#endif
}

#if __has_builtin(__builtin_amdgcn_exp2f)
__device__ __forceinline__ float fexp2(float x) { return __builtin_amdgcn_exp2f(x); }
#else
__device__ __forceinline__ float fexp2(float x) { return exp2f(x); }
#endif
#if __has_builtin(__builtin_amdgcn_rcpf)
__device__ __forceinline__ float frcp(float x) { return __builtin_amdgcn_rcpf(x); }
#else
__device__ __forceinline__ float frcp(float x) { return 1.0f / x; }
#endif

// inputs already pre-scaled by SC_ZR / SC_H
__device__ __forceinline__ float sigm_pre(float zp) {
    return frcp(1.0f + fexp2(zp));
}
__device__ __forceinline__ float tanh_pre(float sp) {
    return 1.0f - 2.0f * frcp(1.0f + fexp2(sp));
}

// lgkm-only barrier: LDS writes visible, in-flight global loads NOT drained
#define BARRIER_LGKM() asm volatile("s_waitcnt lgkmcnt(0)\n\ts_barrier" ::: "memory")

// xzh layout: [gb(32)][t(1024)][col(768)][b4(4)] bf16 (proven R4: sequential
// per-block streams). col<512: xz+b_zr; col>=512: xh+b_h.
#define TSTR2 3072                       // shorts per t within a gb stream
#define GSTR  ((size_t)T_ * TSTR2)       // shorts per gb group
#define WTSZ  (768 * 256)                // shorts per Wt copy (layout below)

// ---------------------------------------------------------------------------
// wt_kernel: Wt stored in WAVE-COALESCED MFMA B-FRAGMENT ORDER (R10 change):
//   Wt[tile(48)][kk(8)][c16(16)][q(4)][j(8)] bf16,
//   holding W'[k = kk*32 + q*8 + j][col = tile*16 + c16], pre-scaled.
// proj's lane (q,c16) then reads its us8 at slot (c16*4+q)*8 within ONE
// contiguous 1-KB segment per (tile,kk) — fully coalesced, one address per
// wave. The old [col][k] layout made every B-load a 64-line gather (16/64 B
// per line used, 4x L2 overfetch) — the dominant proj cost (~300us vs ~70
// floor). Replicated `ncopies` times for per-bb L2 locality.
// ---------------------------------------------------------------------------
__global__ __launch_bounds__(64) void wt_kernel(
    const float* __restrict__ Wzr, const float* __restrict__ Wh,
    unsigned short* __restrict__ Wt, int ncopies)
{
    const int c = blockIdx.x;      // 0..767 (output column)
    const int lane = threadIdx.x;  // 0..63, holds k = 4*lane .. 4*lane+3
    const float* Wp; int ldw, cc;
    if (c < 512) { Wp = Wzr; ldw = 512; cc = c; }
    else         { Wp = Wh;  ldw = 256; cc = c - 512; }
    const float sc = (c < 512) ? SC_ZR : SC_H;
    const int k0 = lane * 4;
    const float a = sc * Wp[(size_t)(k0 + 0) * ldw + cc];
    const float b = sc * Wp[(size_t)(k0 + 1) * ldw + cc];
    const float d = sc * Wp[(size_t)(k0 + 2) * ldw + cc];
    const float e = sc * Wp[(size_t)(k0 + 3) * ldw + cc];
    uint2 u; u.x = pk_bf16(a, b); u.y = pk_bf16(d, e);
    // k = 4*lane + i -> kk = lane>>3, q = (lane&7)>>1, j = (lane&1)*4 + i
    const int tile = c >> 4, c16 = c & 15;
    const int kk = lane >> 3, q = (lane & 7) >> 1, jb = (lane & 1) * 4;
    const size_t frag = ((size_t)(tile * 8 + kk) * 64 + c16 * 4 + q) * 8 + jb;
    for (int r = 0; r < ncopies; ++r)
        *reinterpret_cast<uint2*>(&Wt[(size_t)r * WTSZ + frag]) = u;
}

// ---------------------------------------------------------------------------
// proj: xzh = x @ [W_zr | W_h] + bias (pre-scaled), bf16 out. Proven R4 form;
// only the Wt addressing changed (coalesced frag layout).
// ---------------------------------------------------------------------------
#define LPA 264  // ldsA row pad (shorts): 528 B rows, 16-B aligned

__global__ __launch_bounds__(256, 4) void proj_kernel(
    const float* __restrict__ x, const unsigned short* __restrict__ Wt,
    const float* __restrict__ bzr, const float* __restrict__ bh,
    unsigned short* __restrict__ xzh, size_t wtstride)
{
    const int tid  = threadIdx.x;
    const int lane = tid & 63;
    const int wv   = tid >> 6;
    const int q    = lane >> 4;
    const int c16  = lane & 15;
    const int bb = blockIdx.x >> 8;   // batch block (16 b)
    const int tb = blockIdx.x & 255;  // time block (4 t)

    __shared__ __align__(16) unsigned short ldsA[64 * LPA];

    // ---- stage A (64 rows x 256 k), coalesced: one full row per instr ----
    {
        const int r0 = wv * 16;
#pragma unroll
        for (int r = 0; r < 16; ++r) {
            const int row = r0 + r;
            const float* xr = x + (((size_t)(bb * 16 + (row & 15))) * T_
                                   + tb * 4 + (row >> 4)) * D_;
            f32x4 v = *reinterpret_cast<const f32x4*>(xr + lane * 4);
            uint2 u; u.x = pk_bf16(v[0], v[1]); u.y = pk_bf16(v[2], v[3]);
            *reinterpret_cast<uint2*>(&ldsA[row * LPA + lane * 4]) = u;
        }
    }
    __syncthreads();

    // ---- A fragments to regs: rows (wv>>1)*32 + m2*16 + c16 ----
    const int R0 = (wv >> 1) * 32;
    us8 af[2][8];
#pragma unroll
    for (int m2 = 0; m2 < 2; ++m2)
#pragma unroll
        for (int kk = 0; kk < 8; ++kk)
            af[m2][kk] = *reinterpret_cast<const us8*>(
                &ldsA[(R0 + m2 * 16 + c16) * LPA + kk * 32 + q * 8]);

    // Wt frag pointers: tile t = ch*4 + wn*2 + n2; addr = (t*8+kk)*512 + lofs
    const int wn = wv & 1;
    const int lofs = (c16 * 4 + q) * 8;
    const unsigned short* p0 = Wt + (size_t)bb * wtstride
                               + ((size_t)(wn * 2) * 8) * 512 + lofs;
    const unsigned short* p1 = p0 + 8 * 512;   // next 16-col tile

#pragma unroll 1
    for (int ch = 0; ch < 12; ++ch) {
        f32x4 acc[2][2] = {};
#pragma unroll
        for (int kk = 0; kk < 8; ++kk) {
            us8 w0 = *reinterpret_cast<const us8*>(p0 + kk * 512);
            us8 w1 = *reinterpret_cast<const us8*>(p1 + kk * 512);
#pragma unroll
            for (int m2 = 0; m2 < 2; ++m2) {
                acc[m2][0] = __builtin_amdgcn_mfma_f32_16x16x32_bf16(
                    __builtin_bit_cast(bfrag, af[m2][kk]), __builtin_bit_cast(bfrag, w0),
                    acc[m2][0], 0, 0, 0);
                acc[m2][1] = __builtin_amdgcn_mfma_f32_16x16x32_bf16(
                    __builtin_bit_cast(bfrag, af[m2][kk]), __builtin_bit_cast(bfrag, w1),
                    acc[m2][1], 0, 0, 0);
            }
        }
#pragma unroll
        for (int n2 = 0; n2 < 2; ++n2) {
            const int gcn = ch * 64 + wn * 32 + n2 * 16 + c16;
            const float bias = (gcn < 512) ? (SC_ZR * bzr[gcn])
                                           : (SC_H * bh[gcn - 512]);
#pragma unroll
            for (int m2 = 0; m2 < 2; ++m2) {
                const int t = tb * 4 + (wv >> 1) * 2 + m2;
                uint2 uu;
                uu.x = pk_bf16(acc[m2][n2][0] + bias, acc[m2][n2][1] + bias);
                uu.y = pk_bf16(acc[m2][n2][2] + bias, acc[m2][n2][3] + bias);
                // C-rows q*4+0..3 = batches bb*16+q*4+0..3 -> gb = bb*4+q,
                // b4 = i. gb-major: ((gb*T + t)*768 + col)*4 + b4
                *reinterpret_cast<uint2*>(
                    &xzh[((((size_t)(bb * 4 + q)) * T_ + t) * 768 + gcn) * 4]) = uu;
            }
        }
        p0 += 4 * 8 * 512; p1 += 4 * 8 * 512;   // advance 4 tiles (64 cols)
    }
}

// ---------------------------------------------------------------------------
// gru_rec: byte-identical to the proven R4 1343us kernel. M=4 batch rows per
// block x 32 blocks; broadcast-A MFMA (lane owns batch q via acc[..][0]);
// gb-major sequential xzh streams; single-step loop, rotate prefetch,
// single 8-deep MFMA chains.
// ---------------------------------------------------------------------------
#define HBP 272  // shorts per row (544 B: 34 x 16B, 2-way-max bank quads)

__global__ __launch_bounds__(512, 2) void gru_rec(
    const float* __restrict__ Uzr, const float* __restrict__ Uh,
    const unsigned short* __restrict__ xzh, float* __restrict__ out)
{
    const int tid  = threadIdx.x;
    const int lane = tid & 63;
    const int w    = tid >> 6;
    const int q    = lane >> 4;
    const int c16  = lane & 15;
    const int g    = blockIdx.x;        // 0..31, batch rows g*4 .. g*4+3

    __shared__ __align__(16) unsigned short hb[4 * HBP];
    __shared__ __align__(16) unsigned short rhb[4 * HBP];

    // weight preload, k-perm: position p=kk*32+q*8+j holds h-row
    // kr = kk*32 + q*4 + (j>>1) + 16*(j&1); gate scale folded in.
    us8 wA[4][8];
#pragma unroll
    for (int nt = 0; nt < 4; ++nt) {
        const int col = (nt < 2) ? (w * 32 + nt * 16 + c16)
                                 : (256 + w * 32 + (nt - 2) * 16 + c16);
#pragma unroll
        for (int kk = 0; kk < 8; ++kk) {
            us8 v;
#pragma unroll
            for (int j = 0; j < 8; ++j) {
                const int kr = kk * 32 + q * 4 + (j >> 1) + 16 * (j & 1);
                v[j] = f2bf(SC_ZR * Uzr[(size_t)kr * 512 + col]);
            }
            wA[nt][kk] = v;
        }
    }
    us8 wB[2][8];
#pragma unroll
    for (int nt = 0; nt < 2; ++nt) {
        const int col = w * 32 + nt * 16 + c16;
#pragma unroll
        for (int kk = 0; kk < 8; ++kk) {
            us8 v;
#pragma unroll
            for (int j = 0; j < 8; ++j) {
                const int kr = kk * 32 + q * 4 + (j >> 1) + 16 * (j & 1);
                v[j] = f2bf(SC_H * Uh[(size_t)kr * 256 + col]);
            }
            wB[nt][kk] = v;
        }
    }

    for (int i = tid; i < 4 * HBP; i += 512) { hb[i] = 0; rhb[i] = 0; }
    __syncthreads();

    // per-lane h state: batch g*4+q, cols w*32+c16 (h0) and w*32+16+c16 (h1)
    float h0 = 0.0f, h1 = 0.0f;

    // per-lane xzh offsets (shorts), gb-major layout; the 4 q-lanes tile the
    // b4 group so a wave's 64 lanes read one contiguous 128-B line per nt.
    size_t laneA[4], laneB[2];
#pragma unroll
    for (int nt = 0; nt < 4; ++nt) {
        const int col = (nt < 2) ? (w * 32 + nt * 16 + c16)
                                 : (256 + w * 32 + (nt - 2) * 16 + c16);
        laneA[nt] = (size_t)g * GSTR + (size_t)col * 4 + q;
    }
#pragma unroll
    for (int nt = 0; nt < 2; ++nt)
        laneB[nt] = (size_t)g * GSTR
                    + (size_t)(512 + w * 32 + nt * 16 + c16) * 4 + q;

    // prefetch t=0
    unsigned short ca[4], cxh[2];
#pragma unroll
    for (int nt = 0; nt < 4; ++nt) ca[nt] = xzh[laneA[nt]];
#pragma unroll
    for (int nt = 0; nt < 2; ++nt) cxh[nt] = xzh[laneB[nt]];

    size_t toff = TSTR2;  // points at t+1 data

    const int dwr = q * HBP + w * 32 + 2 * c16;        // row-q packed-dword write
    const int ard = (c16 >> 2) * HBP + q * 8;          // A-frag read base (row dup)

#pragma unroll 1
    for (int t = 0; t < T_; ++t) {
        // issue next step's prefetch (lands any time before end of step)
        unsigned short na[4], nxh[2];
#pragma unroll
        for (int nt = 0; nt < 4; ++nt) na[nt] = xzh[laneA[nt] + toff];
#pragma unroll
        for (int nt = 0; nt < 2; ++nt) nxh[nt] = xzh[laneB[nt] + toff];
        if (t < 1022) toff += TSTR2;

        // ---- phase A: z' = xz' + h @ U_zr' (pre-scaled) ----
        f32x4 acc[4];
#pragma unroll
        for (int nt = 0; nt < 4; ++nt) {
            const float v = bf2f(ca[nt]);
            acc[nt][0] = v; acc[nt][1] = v; acc[nt][2] = v; acc[nt][3] = v;
        }
#pragma unroll
        for (int kk = 0; kk < 8; ++kk) {
            bfrag af = __builtin_bit_cast(bfrag,
                *reinterpret_cast<const us8*>(&hb[ard + kk * 32]));
#pragma unroll
            for (int nt = 0; nt < 4; ++nt)
                acc[nt] = __builtin_amdgcn_mfma_f32_16x16x32_bf16(
                    af, __builtin_bit_cast(bfrag, wA[nt][kk]), acc[nt], 0, 0, 0);
        }
        // R epilogue: this lane owns batch q only (acc[..][0] == row q*4).
        {
            const float r0 = sigm_pre(acc[2][0]);
            const float r1 = sigm_pre(acc[3][0]);
            *reinterpret_cast<unsigned int*>(&rhb[dwr]) = pk_hu(r0 * h0, r1 * h1);
        }
        BARRIER_LGKM();

        // ---- phase B: s' = xh' + (R*h) @ U_h' (pre-scaled) ----
        f32x4 acc2[2];
#pragma unroll
        for (int nt = 0; nt < 2; ++nt) {
            const float v = bf2f(cxh[nt]);
            acc2[nt][0] = v; acc2[nt][1] = v; acc2[nt][2] = v; acc2[nt][3] = v;
        }
#pragma unroll
        for (int kk = 0; kk < 8; ++kk) {
            bfrag rf = __builtin_bit_cast(bfrag,
                *reinterpret_cast<const us8*>(&rhb[ard + kk * 32]));
#pragma unroll
            for (int nt = 0; nt < 2; ++nt)
                acc2[nt] = __builtin_amdgcn_mfma_f32_16x16x32_bf16(
                    rf, __builtin_bit_cast(bfrag, wB[nt][kk]), acc2[nt], 0, 0, 0);
        }
        // Z-sigmoids here (R4 trick): inputs ready since phase A; issue
        // overlaps the matrix-pipe drain of the phase-B MFMAs above.
        {
            const float z0 = sigm_pre(acc[0][0]);
            const float z1 = sigm_pre(acc[1][0]);
            const float s0 = tanh_pre(acc2[0][0]);
            const float s1 = tanh_pre(acc2[1][0]);
            h0 = fmaf(z0, s0 - h0, h0);
            h1 = fmaf(z1, s1 - h1, h1);
            *reinterpret_cast<unsigned int*>(&hb[dwr]) = pk_hu(h0, h1);
        }
        // rotate prefetch
#pragma unroll
        for (int nt = 0; nt < 4; ++nt) ca[nt] = na[nt];
#pragma unroll
        for (int nt = 0; nt < 2; ++nt) cxh[nt] = nxh[nt];
        BARRIER_LGKM();
    }

    // ---- write h_last: batch g*4+q, cols w*32+c16 / +16 ----
    out[(size_t)(g * 4 + q) * 256 + w * 32 + c16] = h0;
    out[(size_t)(g * 4 + q) * 256 + w * 32 + 16 + c16] = h1;
}

extern "C" void kernel_launch(void* const* d_in, const int* in_sizes, int n_in,
                              void* d_out, int out_size, void* d_ws, size_t ws_size,
                              hipStream_t stream) {
    const float* x   = (const float*)d_in[0];
    const float* Wzr = (const float*)d_in[1];
    const float* Uzr = (const float*)d_in[2];
    const float* bzr = (const float*)d_in[3];
    const float* Wh  = (const float*)d_in[4];
    const float* Uh  = (const float*)d_in[5];
    const float* bh  = (const float*)d_in[6];
    float* out = (float*)d_out;

    // ws layout: [xzh 201326592 B][Wt replicas]. Same footprint as R-series.
    const size_t xzhbytes = (size_t)32 * GSTR * 2;   // 201326592
    const size_t wtbytes  = (size_t)WTSZ * 2;        // 393216 per copy
    int ncopies = (ws_size >= xzhbytes + 8 * wtbytes) ? 8
                : (ws_size >= xzhbytes + wtbytes) ? 1 : 1;
    unsigned short* xzh = (unsigned short*)d_ws;
    unsigned short* Wt  = (unsigned short*)((char*)d_ws + xzhbytes);
    const size_t wtstride = (ncopies == 8) ? (size_t)WTSZ : 0;  // shorts per bb replica

    wt_kernel<<<dim3(768), dim3(64), 0, stream>>>(Wzr, Wh, Wt, ncopies);
    proj_kernel<<<dim3(2048), dim3(256), 0, stream>>>(x, Wt, bzr, bh, xzh, wtstride);
    gru_rec<<<dim3(32), dim3(512), 0, stream>>>(Uzr, Uh, xzh, out);
}